// Round 1
// baseline (1174.630 us; speedup 1.0000x reference)
//
#include <hip/hip_runtime.h>
#include <hip/hip_bf16.h>

#define SPLIT 64

// ---------------- Phase 1: fused norm + logits GEMM + softmax ----------------
// Block = 256 threads, tile = 64 points x 64 clusters, full C=256 in 4 chunks of 64.
__global__ __launch_bounds__(256) void p1_logits(
    const float* __restrict__ feat, const int* __restrict__ bids,
    const float* __restrict__ convw, const float* __restrict__ convb,
    float* __restrict__ soft, float* __restrict__ invn, int* __restrict__ cnts, int N)
{
    __shared__ float xs[64 * 68];   // 64 pts x 64 c, stride 68 (16B aligned, conflict-free)
    __shared__ float wsm[64 * 68];  // 64 k x 64 c
    __shared__ float lg[64 * 65];   // logits tile
    __shared__ float ssq[64];
    __shared__ int cnt[8];

    const int t = threadIdx.x;
    if (t < 8) cnt[t] = 0;
    const int p0 = blockIdx.x * 64;
    const int tx = t & 15, ty = t >> 4;   // k = tx + 16j, p = ty + 16i

    float acc[4][4] = {};
    float ssa[4] = {};

    for (int c0 = 0; c0 < 256; c0 += 64) {
        __syncthreads();
        // stage x tile: 4 passes, 16 rows x 16 float4 each
        #pragma unroll
        for (int pass = 0; pass < 4; ++pass) {
            int p = (t >> 4) + 16 * pass;
            int c = (t & 15) * 4;
            float4 val = make_float4(0.f, 0.f, 0.f, 0.f);
            int gp = p0 + p;
            if (gp < N) val = *(const float4*)(feat + (size_t)gp * 256 + c0 + c);
            *(float4*)(xs + p * 68 + c) = val;
        }
        // stage w tile: 64 rows x 16 float4, 4 passes
        {
            int k = t >> 2;
            int cb = t & 3;
            #pragma unroll
            for (int pass = 0; pass < 4; ++pass) {
                int c = (cb + 4 * pass) * 4;
                *(float4*)(wsm + k * 68 + c) = *(const float4*)(convw + k * 256 + c0 + c);
            }
        }
        __syncthreads();
        #pragma unroll
        for (int cc = 0; cc < 64; cc += 4) {
            float4 xv[4], wv[4];
            #pragma unroll
            for (int i = 0; i < 4; ++i) xv[i] = *(const float4*)(xs + (ty + 16 * i) * 68 + cc);
            #pragma unroll
            for (int j = 0; j < 4; ++j) wv[j] = *(const float4*)(wsm + (tx + 16 * j) * 68 + cc);
            #pragma unroll
            for (int i = 0; i < 4; ++i)
                #pragma unroll
                for (int j = 0; j < 4; ++j)
                    acc[i][j] += xv[i].x * wv[j].x + xv[i].y * wv[j].y +
                                 xv[i].z * wv[j].z + xv[i].w * wv[j].w;
            if (tx == 0) {
                #pragma unroll
                for (int i = 0; i < 4; ++i)
                    ssa[i] += xv[i].x * xv[i].x + xv[i].y * xv[i].y +
                              xv[i].z * xv[i].z + xv[i].w * xv[i].w;
            }
        }
    }
    __syncthreads();
    #pragma unroll
    for (int i = 0; i < 4; ++i)
        #pragma unroll
        for (int j = 0; j < 4; ++j)
            lg[(ty + 16 * i) * 65 + (tx + 16 * j)] = acc[i][j];
    if (tx == 0) {
        #pragma unroll
        for (int i = 0; i < 4; ++i) ssq[ty + 16 * i] = ssa[i];
    }
    __syncthreads();

    // softmax: wave w handles 16 points, lane = cluster
    const int wv_ = t >> 6, lane = t & 63;
    for (int r = 0; r < 16; ++r) {
        int p = wv_ * 16 + r;
        int gp = p0 + p;
        if (gp >= N) break;
        float inv = 1.0f / sqrtf(fmaxf(ssq[p], 1e-24f));
        float val = lg[p * 65 + lane] * inv + convb[lane];
        float m = val;
        #pragma unroll
        for (int off = 32; off >= 1; off >>= 1) m = fmaxf(m, __shfl_xor(m, off));
        float e = __expf(val - m);
        float s = e;
        #pragma unroll
        for (int off = 32; off >= 1; off >>= 1) s += __shfl_xor(s, off);
        soft[(size_t)gp * 64 + lane] = e / s;
        if (lane == 0) {
            invn[gp] = inv;
            atomicAdd(&cnt[bids[gp]], 1);
        }
    }
    __syncthreads();
    if (t < 8) atomicAdd(&cnts[t], cnt[t]);
}

// ---------------- Phase 2: prefix + counting-sort scatter ----------------
__global__ void p2_offsets(const int* __restrict__ cnts, int* __restrict__ offs, int* __restrict__ cur)
{
    if (threadIdx.x == 0) {
        int acc = 0;
        for (int b = 0; b < 8; ++b) { offs[b] = acc; cur[b] = acc; acc += cnts[b]; }
        offs[8] = acc;
    }
}

__global__ __launch_bounds__(256) void p2_scatter(
    const int* __restrict__ bids, int* __restrict__ cur, int* __restrict__ perm, int N)
{
    __shared__ int lcnt[8], lbase[8];
    const int t = threadIdx.x;
    if (t < 8) lcnt[t] = 0;
    __syncthreads();
    int p = blockIdx.x * 256 + t;
    int b = 0, my = 0;
    bool ok = p < N;
    if (ok) { b = bids[p]; my = atomicAdd(&lcnt[b], 1); }
    __syncthreads();
    if (t < 8) lbase[t] = atomicAdd(&cur[t], lcnt[t]);
    __syncthreads();
    if (ok) perm[lbase[b] + my] = p;
}

// ---------------- Phase 3: per-batch aggregation A_b = Soft_b^T X_b ----------------
// Block = 256 threads owns full 64k x 256c output tile (64 acc/thread), loops points in chunks of 16.
__global__ __launch_bounds__(256) void p3_aggregate(
    const float* __restrict__ feat, const float* __restrict__ soft,
    const float* __restrict__ invn, const int* __restrict__ perm,
    const int* __restrict__ offs, float* __restrict__ A, float* __restrict__ S)
{
    __shared__ float xs[16 * 256];  // 16 pts x 256 c (normalized)
    __shared__ float sf[16 * 64];   // 16 pts x 64 k

    const int b = blockIdx.x / SPLIT, sp = blockIdx.x % SPLIT;
    const int start = offs[b], end = offs[b + 1];
    const int len = end - start;
    const int chunk = (len + SPLIT - 1) / SPLIT;
    const int s0 = start + sp * chunk;
    const int s1 = min(s0 + chunk, end);

    const int t = threadIdx.x;
    const int tx = t & 31, ty = t >> 5;  // c = tx + 32*ci, k = ty*8 + j
    float acc[8][8] = {};
    float sacc = 0.f;

    for (int q0 = s0; q0 < s1; q0 += 16) {
        __syncthreads();
        {
            int r = t >> 4;       // 0..15 point row
            int c4 = t & 15;      // float4 index
            int q = q0 + r;
            if (q < s1) {
                int gp = perm[q];
                float iv = invn[gp];
                const float4* src = (const float4*)(feat + (size_t)gp * 256);
                #pragma unroll
                for (int pass = 0; pass < 4; ++pass) {
                    float4 vw = src[c4 + 16 * pass];
                    vw.x *= iv; vw.y *= iv; vw.z *= iv; vw.w *= iv;
                    *(float4*)(xs + r * 256 + (c4 + 16 * pass) * 4) = vw;
                }
                ((float4*)(sf + r * 64))[c4] = ((const float4*)(soft + (size_t)gp * 64))[c4];
            } else {
                #pragma unroll
                for (int pass = 0; pass < 4; ++pass)
                    *(float4*)(xs + r * 256 + (c4 + 16 * pass) * 4) = make_float4(0.f, 0.f, 0.f, 0.f);
                ((float4*)(sf + r * 64))[c4] = make_float4(0.f, 0.f, 0.f, 0.f);
            }
        }
        __syncthreads();
        for (int i = 0; i < 16; ++i) {
            float xvals[8];
            #pragma unroll
            for (int ci = 0; ci < 8; ++ci) xvals[ci] = xs[i * 256 + tx + 32 * ci];  // bank = tx, conflict-free
            float4 sva = *(const float4*)(sf + i * 64 + ty * 8);
            float4 svb = *(const float4*)(sf + i * 64 + ty * 8 + 4);
            float sv[8] = {sva.x, sva.y, sva.z, sva.w, svb.x, svb.y, svb.z, svb.w};
            #pragma unroll
            for (int j = 0; j < 8; ++j)
                #pragma unroll
                for (int ci = 0; ci < 8; ++ci)
                    acc[j][ci] += sv[j] * xvals[ci];
        }
        if (t < 64) {
            #pragma unroll
            for (int i = 0; i < 16; ++i) sacc += sf[i * 64 + t];
        }
    }

    float* Ab = A + b * 16384;
    #pragma unroll
    for (int j = 0; j < 8; ++j) {
        int k = ty * 8 + j;
        #pragma unroll
        for (int ci = 0; ci < 8; ++ci)
            atomicAdd(Ab + k * 256 + tx + 32 * ci, acc[j][ci]);
    }
    if (t < 64) atomicAdd(S + b * 64 + t, sacc);
}

// ---------------- Phase 4a: vlad = A - S*centroid, intra-normalize ----------------
__global__ __launch_bounds__(256) void p4a_vlad(
    const float* __restrict__ A, const float* __restrict__ S,
    const float* __restrict__ cents, float* __restrict__ v)
{
    const int b = blockIdx.x >> 6, k = blockIdx.x & 63;
    const int t = threadIdx.x;
    float val = A[b * 16384 + k * 256 + t] - S[b * 64 + k] * cents[k * 256 + t];
    float sq = val * val;
    #pragma unroll
    for (int off = 32; off >= 1; off >>= 1) sq += __shfl_xor(sq, off);
    __shared__ float wsum[4];
    if ((t & 63) == 0) wsum[t >> 6] = sq;
    __syncthreads();
    float tot = wsum[0] + wsum[1] + wsum[2] + wsum[3];
    float r = 1.0f / fmaxf(sqrtf(tot), 1e-12f);
    v[b * 16384 + k * 256 + t] = val * r;
}

// ---------------- Phase 4b: FC out = v @ fc_w.T + fc_b ----------------
__global__ __launch_bounds__(256) void p4b_fc(
    const float* __restrict__ v, const float* __restrict__ fcw,
    const float* __restrict__ fcb, float* __restrict__ pre)
{
    const int t = threadIdx.x;
    const int o0 = blockIdx.x * 4;
    float acc[4][8] = {};
    for (int it = 0; it < 64; ++it) {
        int i = it * 256 + t;
        float wv[4];
        #pragma unroll
        for (int oo = 0; oo < 4; ++oo) wv[oo] = fcw[(size_t)(o0 + oo) * 16384 + i];
        #pragma unroll
        for (int b = 0; b < 8; ++b) {
            float vv = v[b * 16384 + i];
            #pragma unroll
            for (int oo = 0; oo < 4; ++oo) acc[oo][b] += wv[oo] * vv;
        }
    }
    __shared__ float red[32][4];
    #pragma unroll
    for (int oo = 0; oo < 4; ++oo)
        #pragma unroll
        for (int b = 0; b < 8; ++b) {
            float sv = acc[oo][b];
            #pragma unroll
            for (int off = 32; off >= 1; off >>= 1) sv += __shfl_xor(sv, off);
            if ((t & 63) == 0) red[oo * 8 + b][t >> 6] = sv;
        }
    __syncthreads();
    if (t < 32) {
        int oo = t >> 3, b = t & 7;
        float sv = red[t][0] + red[t][1] + red[t][2] + red[t][3];
        pre[b * 1024 + o0 + oo] = sv + fcb[o0 + oo];
    }
}

// ---------------- Phase 5: final l2norm over 1024 ----------------
__global__ __launch_bounds__(256) void p5_norm(const float* __restrict__ pre, float* __restrict__ out)
{
    const int b = blockIdx.x, t = threadIdx.x;
    float vals[4];
    float sq = 0.f;
    #pragma unroll
    for (int i = 0; i < 4; ++i) {
        vals[i] = pre[b * 1024 + t + 256 * i];
        sq += vals[i] * vals[i];
    }
    #pragma unroll
    for (int off = 32; off >= 1; off >>= 1) sq += __shfl_xor(sq, off);
    __shared__ float wsum[4];
    if ((t & 63) == 0) wsum[t >> 6] = sq;
    __syncthreads();
    float tot = wsum[0] + wsum[1] + wsum[2] + wsum[3];
    float r = 1.0f / fmaxf(sqrtf(tot), 1e-12f);
    #pragma unroll
    for (int i = 0; i < 4; ++i) out[b * 1024 + t + 256 * i] = vals[i] * r;
}

extern "C" void kernel_launch(void* const* d_in, const int* in_sizes, int n_in,
                              void* d_out, int out_size, void* d_ws, size_t ws_size,
                              hipStream_t stream)
{
    const float* feat  = (const float*)d_in[0];
    const int*   bids  = (const int*)d_in[1];
    const float* cents = (const float*)d_in[2];
    const float* convw = (const float*)d_in[3];
    const float* convb = (const float*)d_in[4];
    const float* fcw   = (const float*)d_in[5];
    const float* fcb   = (const float*)d_in[6];
    float* out = (float*)d_out;

    const int N = in_sizes[0] / 256;  // 200000

    float* ws   = (float*)d_ws;
    float* soft = ws;                       // N*64
    float* invn = soft + (size_t)N * 64;    // N
    float* A    = invn + N;                 // 8*64*256
    float* S    = A + 8 * 64 * 256;         // 512
    float* v    = S + 512;                  // 8*64*256
    float* pre  = v + 8 * 64 * 256;         // 8192
    int* perm = (int*)(pre + 8192);         // N
    int* cnts = perm + N;                   // 8
    int* offs = cnts + 8;                   // 9
    int* cur  = offs + 9;                   // 8

    hipMemsetAsync(A, 0, (8 * 64 * 256 + 512) * sizeof(float), stream);
    hipMemsetAsync(cnts, 0, 8 * sizeof(int), stream);

    p1_logits<<<(N + 63) / 64, 256, 0, stream>>>(feat, bids, convw, convb, soft, invn, cnts, N);
    p2_offsets<<<1, 64, 0, stream>>>(cnts, offs, cur);
    p2_scatter<<<(N + 255) / 256, 256, 0, stream>>>(bids, cur, perm, N);
    p3_aggregate<<<8 * SPLIT, 256, 0, stream>>>(feat, soft, invn, perm, offs, A, S);
    p4a_vlad<<<512, 256, 0, stream>>>(A, S, cents, v);
    p4b_fc<<<256, 256, 0, stream>>>(v, fcw, fcb, pre);
    p5_norm<<<8, 256, 0, stream>>>(pre, out);
}

// Round 2
// 586.309 us; speedup vs baseline: 2.0034x; 2.0034x over previous
//
#include <hip/hip_runtime.h>
#include <hip/hip_bf16.h>

#define SPLIT 64

typedef __attribute__((ext_vector_type(8))) short bf16x8;
typedef __attribute__((ext_vector_type(4))) float f32x4;

// ---------------- Phase 0: pre-split conv_w into frag-ready hi/lo bf16 ----------------
// Entry e = (ntile*8 + kstep)*64 + lane; lane holds cluster = ntile*16 + (lane&15),
// channels kstep*32 + (lane>>4)*8 .. +8  (MFMA B-operand layout for 16x16x32).
__global__ void p0_wsplit(const float* __restrict__ convw,
                          short* __restrict__ whi, short* __restrict__ wlo)
{
    int e = blockIdx.x * 256 + threadIdx.x;
    if (e >= 2048) return;
    int lane = e & 63;
    int kstep = (e >> 6) & 7;
    int nt = e >> 9;
    int cluster = nt * 16 + (lane & 15);
    int ch0 = kstep * 32 + (lane >> 4) * 8;
    const float* src = convw + cluster * 256 + ch0;
    #pragma unroll
    for (int j = 0; j < 8; ++j) {
        float x = src[j];
        unsigned u = __float_as_uint(x);
        unsigned uh = u & 0xffff0000u;
        float r = x - __uint_as_float(uh);
        whi[e * 8 + j] = (short)(u >> 16);
        wlo[e * 8 + j] = (short)(__float_as_uint(r) >> 16);
    }
}

// ---------------- Phase 1: fused norm + logits (split-bf16 MFMA) + softmax ----------------
// Block = 256 threads = 4 waves; block covers 64 points x 64 clusters; wave covers 16 points.
__global__ __launch_bounds__(256) void p1_mfma(
    const float* __restrict__ feat, const int* __restrict__ bids,
    const short* __restrict__ whi, const short* __restrict__ wlo,
    const float* __restrict__ convb,
    float* __restrict__ soft, float* __restrict__ invn, int* __restrict__ cnts, int N)
{
    __shared__ float ssq_lds[64];
    __shared__ int cnt[8];
    const int t = threadIdx.x;
    if (t < 8) cnt[t] = 0;
    const int w = t >> 6, lane = t & 63;
    const int m = lane & 15, quad = lane >> 4;
    const int p0 = blockIdx.x * 64;
    const int gp = p0 + w * 16 + m;     // point in this lane's A-fragment
    const bool valid = gp < N;

    f32x4 acc[4];
    #pragma unroll
    for (int nt = 0; nt < 4; ++nt) acc[nt] = (f32x4){0.f, 0.f, 0.f, 0.f};
    float ssq = 0.f;

    const float* frow = feat + (size_t)gp * 256 + quad * 8;
    const bf16x8* WH = (const bf16x8*)whi;
    const bf16x8* WL = (const bf16x8*)wlo;

    for (int ks = 0; ks < 8; ++ks) {
        float x[8];
        if (valid) {
            float4 v0 = *(const float4*)(frow + ks * 32);
            float4 v1 = *(const float4*)(frow + ks * 32 + 4);
            x[0] = v0.x; x[1] = v0.y; x[2] = v0.z; x[3] = v0.w;
            x[4] = v1.x; x[5] = v1.y; x[6] = v1.z; x[7] = v1.w;
        } else {
            #pragma unroll
            for (int j = 0; j < 8; ++j) x[j] = 0.f;
        }
        bf16x8 ahi, alo;
        #pragma unroll
        for (int j = 0; j < 8; ++j) {
            unsigned u = __float_as_uint(x[j]);
            unsigned uh = u & 0xffff0000u;
            float r = x[j] - __uint_as_float(uh);
            ahi[j] = (short)(u >> 16);
            alo[j] = (short)(__float_as_uint(r) >> 16);
            ssq += x[j] * x[j];
        }
        #pragma unroll
        for (int nt = 0; nt < 4; ++nt) {
            bf16x8 bhi = WH[(nt * 8 + ks) * 64 + lane];
            bf16x8 blo = WL[(nt * 8 + ks) * 64 + lane];
            acc[nt] = __builtin_amdgcn_mfma_f32_16x16x32_bf16(ahi, bhi, acc[nt], 0, 0, 0);
            acc[nt] = __builtin_amdgcn_mfma_f32_16x16x32_bf16(ahi, blo, acc[nt], 0, 0, 0);
            acc[nt] = __builtin_amdgcn_mfma_f32_16x16x32_bf16(alo, bhi, acc[nt], 0, 0, 0);
        }
    }

    // ||x||^2: lane holds partial over its channels for point m; sum across quads
    ssq += __shfl_xor(ssq, 16);
    ssq += __shfl_xor(ssq, 32);
    if (quad == 0) ssq_lds[w * 16 + m] = ssq;
    __syncthreads();

    // softmax epilogue. C/D layout: col(cluster-in-tile)=lane&15, row(point)=quad*4+r
    float bias[4];
    #pragma unroll
    for (int nt = 0; nt < 4; ++nt) bias[nt] = convb[nt * 16 + m];

    #pragma unroll
    for (int r = 0; r < 4; ++r) {
        int pl = quad * 4 + r;
        int gpt = p0 + w * 16 + pl;
        float inv = rsqrtf(fmaxf(ssq_lds[w * 16 + pl], 1e-24f));
        float v[4];
        #pragma unroll
        for (int nt = 0; nt < 4; ++nt) v[nt] = acc[nt][r] * inv + bias[nt];
        float mx = fmaxf(fmaxf(v[0], v[1]), fmaxf(v[2], v[3]));
        #pragma unroll
        for (int off = 8; off >= 1; off >>= 1) mx = fmaxf(mx, __shfl_xor(mx, off));
        float e[4];
        float s = 0.f;
        #pragma unroll
        for (int nt = 0; nt < 4; ++nt) { e[nt] = __expf(v[nt] - mx); s += e[nt]; }
        #pragma unroll
        for (int off = 8; off >= 1; off >>= 1) s += __shfl_xor(s, off);
        float rs = 1.0f / s;
        if (gpt < N) {
            #pragma unroll
            for (int nt = 0; nt < 4; ++nt)
                soft[(size_t)gpt * 64 + nt * 16 + m] = e[nt] * rs;
            if (m == 0) {
                invn[gpt] = inv;
                atomicAdd(&cnt[bids[gpt]], 1);
            }
        }
    }
    __syncthreads();
    if (t < 8) atomicAdd(&cnts[t], cnt[t]);
}

// ---------------- Phase 2: prefix + counting-sort scatter ----------------
__global__ void p2_offsets(const int* __restrict__ cnts, int* __restrict__ offs, int* __restrict__ cur)
{
    if (threadIdx.x == 0) {
        int acc = 0;
        for (int b = 0; b < 8; ++b) { offs[b] = acc; cur[b] = acc; acc += cnts[b]; }
        offs[8] = acc;
    }
}

__global__ __launch_bounds__(256) void p2_scatter(
    const int* __restrict__ bids, int* __restrict__ cur, int* __restrict__ perm, int N)
{
    __shared__ int lcnt[8], lbase[8];
    const int t = threadIdx.x;
    if (t < 8) lcnt[t] = 0;
    __syncthreads();
    int p = blockIdx.x * 256 + t;
    int b = 0, my = 0;
    bool ok = p < N;
    if (ok) { b = bids[p]; my = atomicAdd(&lcnt[b], 1); }
    __syncthreads();
    if (t < 8) lbase[t] = atomicAdd(&cur[t], lcnt[t]);
    __syncthreads();
    if (ok) perm[lbase[b] + my] = p;
}

// ---------------- Phase 3: per-batch aggregation A_b = Soft_b^T X_b ----------------
__global__ __launch_bounds__(256) void p3_aggregate(
    const float* __restrict__ feat, const float* __restrict__ soft,
    const float* __restrict__ invn, const int* __restrict__ perm,
    const int* __restrict__ offs, float* __restrict__ A, float* __restrict__ S)
{
    __shared__ float xs[16 * 256];
    __shared__ float sf[16 * 64];

    const int b = blockIdx.x / SPLIT, sp = blockIdx.x % SPLIT;
    const int start = offs[b], end = offs[b + 1];
    const int len = end - start;
    const int chunk = (len + SPLIT - 1) / SPLIT;
    const int s0 = start + sp * chunk;
    const int s1 = min(s0 + chunk, end);

    const int t = threadIdx.x;
    const int tx = t & 31, ty = t >> 5;
    float acc[8][8] = {};
    float sacc = 0.f;

    for (int q0 = s0; q0 < s1; q0 += 16) {
        __syncthreads();
        {
            int r = t >> 4;
            int c4 = t & 15;
            int q = q0 + r;
            if (q < s1) {
                int gp = perm[q];
                float iv = invn[gp];
                const float4* src = (const float4*)(feat + (size_t)gp * 256);
                #pragma unroll
                for (int pass = 0; pass < 4; ++pass) {
                    float4 vw = src[c4 + 16 * pass];
                    vw.x *= iv; vw.y *= iv; vw.z *= iv; vw.w *= iv;
                    *(float4*)(xs + r * 256 + (c4 + 16 * pass) * 4) = vw;
                }
                ((float4*)(sf + r * 64))[c4] = ((const float4*)(soft + (size_t)gp * 64))[c4];
            } else {
                #pragma unroll
                for (int pass = 0; pass < 4; ++pass)
                    *(float4*)(xs + r * 256 + (c4 + 16 * pass) * 4) = make_float4(0.f, 0.f, 0.f, 0.f);
                ((float4*)(sf + r * 64))[c4] = make_float4(0.f, 0.f, 0.f, 0.f);
            }
        }
        __syncthreads();
        for (int i = 0; i < 16; ++i) {
            float xvals[8];
            #pragma unroll
            for (int ci = 0; ci < 8; ++ci) xvals[ci] = xs[i * 256 + tx + 32 * ci];
            float4 sva = *(const float4*)(sf + i * 64 + ty * 8);
            float4 svb = *(const float4*)(sf + i * 64 + ty * 8 + 4);
            float sv[8] = {sva.x, sva.y, sva.z, sva.w, svb.x, svb.y, svb.z, svb.w};
            #pragma unroll
            for (int j = 0; j < 8; ++j)
                #pragma unroll
                for (int ci = 0; ci < 8; ++ci)
                    acc[j][ci] += sv[j] * xvals[ci];
        }
        if (t < 64) {
            #pragma unroll
            for (int i = 0; i < 16; ++i) sacc += sf[i * 64 + t];
        }
    }

    float* Ab = A + b * 16384;
    #pragma unroll
    for (int j = 0; j < 8; ++j) {
        int k = ty * 8 + j;
        #pragma unroll
        for (int ci = 0; ci < 8; ++ci)
            atomicAdd(Ab + k * 256 + tx + 32 * ci, acc[j][ci]);
    }
    if (t < 64) atomicAdd(S + b * 64 + t, sacc);
}

// ---------------- Phase 4a: vlad = A - S*centroid, intra-normalize ----------------
__global__ __launch_bounds__(256) void p4a_vlad(
    const float* __restrict__ A, const float* __restrict__ S,
    const float* __restrict__ cents, float* __restrict__ v)
{
    const int b = blockIdx.x >> 6, k = blockIdx.x & 63;
    const int t = threadIdx.x;
    float val = A[b * 16384 + k * 256 + t] - S[b * 64 + k] * cents[k * 256 + t];
    float sq = val * val;
    #pragma unroll
    for (int off = 32; off >= 1; off >>= 1) sq += __shfl_xor(sq, off);
    __shared__ float wsum[4];
    if ((t & 63) == 0) wsum[t >> 6] = sq;
    __syncthreads();
    float tot = wsum[0] + wsum[1] + wsum[2] + wsum[3];
    float r = 1.0f / fmaxf(sqrtf(tot), 1e-12f);
    v[b * 16384 + k * 256 + t] = val * r;
}

// ---------------- Phase 4b: FC out = v @ fc_w.T + fc_b ----------------
__global__ __launch_bounds__(256) void p4b_fc(
    const float* __restrict__ v, const float* __restrict__ fcw,
    const float* __restrict__ fcb, float* __restrict__ pre)
{
    const int t = threadIdx.x;
    const int o0 = blockIdx.x * 4;
    float acc[4][8] = {};
    for (int it = 0; it < 64; ++it) {
        int i = it * 256 + t;
        float wv[4];
        #pragma unroll
        for (int oo = 0; oo < 4; ++oo) wv[oo] = fcw[(size_t)(o0 + oo) * 16384 + i];
        #pragma unroll
        for (int b = 0; b < 8; ++b) {
            float vv = v[b * 16384 + i];
            #pragma unroll
            for (int oo = 0; oo < 4; ++oo) acc[oo][b] += wv[oo] * vv;
        }
    }
    __shared__ float red[32][4];
    #pragma unroll
    for (int oo = 0; oo < 4; ++oo)
        #pragma unroll
        for (int b = 0; b < 8; ++b) {
            float sv = acc[oo][b];
            #pragma unroll
            for (int off = 32; off >= 1; off >>= 1) sv += __shfl_xor(sv, off);
            if ((t & 63) == 0) red[oo * 8 + b][t >> 6] = sv;
        }
    __syncthreads();
    if (t < 32) {
        int oo = t >> 3, b = t & 7;
        float sv = red[t][0] + red[t][1] + red[t][2] + red[t][3];
        pre[b * 1024 + o0 + oo] = sv + fcb[o0 + oo];
    }
}

// ---------------- Phase 5: final l2norm over 1024 ----------------
__global__ __launch_bounds__(256) void p5_norm(const float* __restrict__ pre, float* __restrict__ out)
{
    const int b = blockIdx.x, t = threadIdx.x;
    float vals[4];
    float sq = 0.f;
    #pragma unroll
    for (int i = 0; i < 4; ++i) {
        vals[i] = pre[b * 1024 + t + 256 * i];
        sq += vals[i] * vals[i];
    }
    #pragma unroll
    for (int off = 32; off >= 1; off >>= 1) sq += __shfl_xor(sq, off);
    __shared__ float wsum[4];
    if ((t & 63) == 0) wsum[t >> 6] = sq;
    __syncthreads();
    float tot = wsum[0] + wsum[1] + wsum[2] + wsum[3];
    float r = 1.0f / fmaxf(sqrtf(tot), 1e-12f);
    #pragma unroll
    for (int i = 0; i < 4; ++i) out[b * 1024 + t + 256 * i] = vals[i] * r;
}

extern "C" void kernel_launch(void* const* d_in, const int* in_sizes, int n_in,
                              void* d_out, int out_size, void* d_ws, size_t ws_size,
                              hipStream_t stream)
{
    const float* feat  = (const float*)d_in[0];
    const int*   bids  = (const int*)d_in[1];
    const float* cents = (const float*)d_in[2];
    const float* convw = (const float*)d_in[3];
    const float* convb = (const float*)d_in[4];
    const float* fcw   = (const float*)d_in[5];
    const float* fcb   = (const float*)d_in[6];
    float* out = (float*)d_out;

    const int N = in_sizes[0] / 256;  // 200000

    // workspace layout (16B-aligned chunks first)
    short* whi = (short*)d_ws;                    // 16384 shorts (32 KB)
    short* wlo = whi + 16384;                     // 16384 shorts (32 KB)
    float* soft = (float*)(wlo + 16384);          // N*64
    float* invn = soft + (size_t)N * 64;          // N
    float* A    = invn + N;                       // 8*64*256
    float* S    = A + 8 * 64 * 256;               // 512
    float* v    = S + 512;                        // 8*64*256
    float* pre  = v + 8 * 64 * 256;               // 8192
    int* perm = (int*)(pre + 8192);               // N
    int* cnts = perm + N;                         // 8
    int* offs = cnts + 8;                         // 9
    int* cur  = offs + 9;                         // 8

    hipMemsetAsync(A, 0, (8 * 64 * 256 + 512) * sizeof(float), stream);
    hipMemsetAsync(cnts, 0, 8 * sizeof(int), stream);

    p0_wsplit<<<8, 256, 0, stream>>>(convw, whi, wlo);
    p1_mfma<<<(N + 63) / 64, 256, 0, stream>>>(feat, bids, whi, wlo, convb, soft, invn, cnts, N);
    p2_offsets<<<1, 64, 0, stream>>>(cnts, offs, cur);
    p2_scatter<<<(N + 255) / 256, 256, 0, stream>>>(bids, cur, perm, N);
    p3_aggregate<<<8 * SPLIT, 256, 0, stream>>>(feat, soft, invn, perm, offs, A, S);
    p4a_vlad<<<512, 256, 0, stream>>>(A, S, cents, v);
    p4b_fc<<<256, 256, 0, stream>>>(v, fcw, fcb, pre);
    p5_norm<<<8, 256, 0, stream>>>(pre, out);
}

// Round 3
// 571.524 us; speedup vs baseline: 2.0553x; 1.0259x over previous
//
#include <hip/hip_runtime.h>
#include <hip/hip_bf16.h>

typedef __attribute__((ext_vector_type(8))) short bf16x8;
typedef __attribute__((ext_vector_type(4))) float f32x4;

#define PCAP 768   // max points per p3 block (batch_len/split + slack)

// ---------------- Phase 0: pre-split conv_w into frag-ready hi/lo bf16 ----------------
__global__ void p0_wsplit(const float* __restrict__ convw,
                          short* __restrict__ whi, short* __restrict__ wlo)
{
    int e = blockIdx.x * 256 + threadIdx.x;
    if (e >= 2048) return;
    int lane = e & 63;
    int kstep = (e >> 6) & 7;
    int nt = e >> 9;
    int cluster = nt * 16 + (lane & 15);
    int ch0 = kstep * 32 + (lane >> 4) * 8;
    const float* src = convw + cluster * 256 + ch0;
    #pragma unroll
    for (int j = 0; j < 8; ++j) {
        float x = src[j];
        unsigned u = __float_as_uint(x);
        unsigned uh = u & 0xffff0000u;
        float r = x - __uint_as_float(uh);
        whi[e * 8 + j] = (short)(u >> 16);
        wlo[e * 8 + j] = (short)(__float_as_uint(r) >> 16);
    }
}

// ---------------- Phase 1: fused norm + logits (split-bf16 MFMA) + softmax ----------------
__global__ __launch_bounds__(256) void p1_mfma(
    const float* __restrict__ feat, const int* __restrict__ bids,
    const short* __restrict__ whi, const short* __restrict__ wlo,
    const float* __restrict__ convb,
    float* __restrict__ soft, float* __restrict__ invn, int* __restrict__ cnts, int N)
{
    __shared__ float ssq_lds[64];
    __shared__ int cnt[8];
    const int t = threadIdx.x;
    if (t < 8) cnt[t] = 0;
    const int w = t >> 6, lane = t & 63;
    const int m = lane & 15, quad = lane >> 4;
    const int p0 = blockIdx.x * 64;
    const int gp = p0 + w * 16 + m;
    const bool valid = gp < N;

    f32x4 acc[4];
    #pragma unroll
    for (int nt = 0; nt < 4; ++nt) acc[nt] = (f32x4){0.f, 0.f, 0.f, 0.f};
    float ssq = 0.f;

    const float* frow = feat + (size_t)gp * 256 + quad * 8;
    const bf16x8* WH = (const bf16x8*)whi;
    const bf16x8* WL = (const bf16x8*)wlo;

    for (int ks = 0; ks < 8; ++ks) {
        float x[8];
        if (valid) {
            float4 v0 = *(const float4*)(frow + ks * 32);
            float4 v1 = *(const float4*)(frow + ks * 32 + 4);
            x[0] = v0.x; x[1] = v0.y; x[2] = v0.z; x[3] = v0.w;
            x[4] = v1.x; x[5] = v1.y; x[6] = v1.z; x[7] = v1.w;
        } else {
            #pragma unroll
            for (int j = 0; j < 8; ++j) x[j] = 0.f;
        }
        bf16x8 ahi, alo;
        #pragma unroll
        for (int j = 0; j < 8; ++j) {
            unsigned u = __float_as_uint(x[j]);
            unsigned uh = u & 0xffff0000u;
            float r = x[j] - __uint_as_float(uh);
            ahi[j] = (short)(u >> 16);
            alo[j] = (short)(__float_as_uint(r) >> 16);
            ssq += x[j] * x[j];
        }
        #pragma unroll
        for (int nt = 0; nt < 4; ++nt) {
            bf16x8 bhi = WH[(nt * 8 + ks) * 64 + lane];
            bf16x8 blo = WL[(nt * 8 + ks) * 64 + lane];
            acc[nt] = __builtin_amdgcn_mfma_f32_16x16x32_bf16(ahi, bhi, acc[nt], 0, 0, 0);
            acc[nt] = __builtin_amdgcn_mfma_f32_16x16x32_bf16(ahi, blo, acc[nt], 0, 0, 0);
            acc[nt] = __builtin_amdgcn_mfma_f32_16x16x32_bf16(alo, bhi, acc[nt], 0, 0, 0);
        }
    }

    ssq += __shfl_xor(ssq, 16);
    ssq += __shfl_xor(ssq, 32);
    if (quad == 0) ssq_lds[w * 16 + m] = ssq;
    __syncthreads();

    float bias[4];
    #pragma unroll
    for (int nt = 0; nt < 4; ++nt) bias[nt] = convb[nt * 16 + m];

    #pragma unroll
    for (int r = 0; r < 4; ++r) {
        int pl = quad * 4 + r;
        int gpt = p0 + w * 16 + pl;
        float inv = rsqrtf(fmaxf(ssq_lds[w * 16 + pl], 1e-24f));
        float v[4];
        #pragma unroll
        for (int nt = 0; nt < 4; ++nt) v[nt] = acc[nt][r] * inv + bias[nt];
        float mx = fmaxf(fmaxf(v[0], v[1]), fmaxf(v[2], v[3]));
        #pragma unroll
        for (int off = 8; off >= 1; off >>= 1) mx = fmaxf(mx, __shfl_xor(mx, off));
        float e[4];
        float s = 0.f;
        #pragma unroll
        for (int nt = 0; nt < 4; ++nt) { e[nt] = __expf(v[nt] - mx); s += e[nt]; }
        #pragma unroll
        for (int off = 8; off >= 1; off >>= 1) s += __shfl_xor(s, off);
        float rs = 1.0f / s;
        if (gpt < N) {
            #pragma unroll
            for (int nt = 0; nt < 4; ++nt)
                soft[(size_t)gpt * 64 + nt * 16 + m] = e[nt] * rs;
            if (m == 0) {
                invn[gpt] = inv;
                atomicAdd(&cnt[bids[gpt]], 1);
            }
        }
    }
    __syncthreads();
    if (t < 8) atomicAdd(&cnts[t], cnt[t]);
}

// ---------------- Phase 2: prefix + counting-sort scatter ----------------
__global__ void p2_offsets(const int* __restrict__ cnts, int* __restrict__ offs, int* __restrict__ cur)
{
    if (threadIdx.x == 0) {
        int acc = 0;
        for (int b = 0; b < 8; ++b) { offs[b] = acc; cur[b] = acc; acc += cnts[b]; }
        offs[8] = acc;
    }
}

__global__ __launch_bounds__(256) void p2_scatter(
    const int* __restrict__ bids, int* __restrict__ cur, int* __restrict__ perm, int N)
{
    __shared__ int lcnt[8], lbase[8];
    const int t = threadIdx.x;
    if (t < 8) lcnt[t] = 0;
    __syncthreads();
    int p = blockIdx.x * 256 + t;
    int b = 0, my = 0;
    bool ok = p < N;
    if (ok) { b = bids[p]; my = atomicAdd(&lcnt[b], 1); }
    __syncthreads();
    if (t < 8) lbase[t] = atomicAdd(&cur[t], lcnt[t]);
    __syncthreads();
    if (ok) perm[lbase[b] + my] = p;
}

// ---------------- Phase 3: per-batch aggregation via split-bf16 MFMA ----------------
// Block = 256 thr = 4 waves; block owns full 64k x 256c tile for (batch b, point-slice sp).
// LDS staged TRANSPOSED ([c][p] / [k][p]) so A/B frags are single b128 reads.
__global__ __launch_bounds__(256) void p3_mfma(
    const float* __restrict__ feat, const float* __restrict__ soft,
    const float* __restrict__ invn, const int* __restrict__ perm,
    const int* __restrict__ offs, float* __restrict__ partial,
    float* __restrict__ S, int split)
{
    __shared__ short xsT_hi[256 * 32];  // [c][p] 16 KB
    __shared__ short xsT_lo[256 * 32];  // 16 KB
    __shared__ short sT_hi[64 * 32];    // [k][p] 4 KB
    __shared__ short sT_lo[64 * 32];    // 4 KB
    __shared__ int   pidxL[PCAP];
    __shared__ float invL[PCAP];

    const int b  = blockIdx.x / split;
    const int sp = blockIdx.x % split;
    const int start = offs[b], end = offs[b + 1];
    const int len = end - start;
    const int chunk = (len + split - 1) / split;
    const int s0 = start + sp * chunk;
    int myLen = end - s0;
    myLen = max(0, min(myLen, chunk));
    myLen = min(myLen, PCAP);

    const int t = threadIdx.x;
    const int w = t >> 6, lane = t & 63;
    const int m = lane & 15, quad = lane >> 4;

    for (int i = t; i < myLen; i += 256) pidxL[i] = perm[s0 + i];
    __syncthreads();
    for (int i = t; i < myLen; i += 256) invL[i] = invn[pidxL[i]];
    __syncthreads();

    f32x4 acc[16];
    #pragma unroll
    for (int ct = 0; ct < 16; ++ct) acc[ct] = (f32x4){0.f, 0.f, 0.f, 0.f};
    float sacc = 0.f;

    const int nch = (myLen + 31) >> 5;
    for (int q = 0; q < nch; ++q) {
        const int p0 = q * 32;
        // per-wave point metadata for its 8-point subgroup
        int pids[8];
        float pinv[8];
        #pragma unroll
        for (int j = 0; j < 8; ++j) {
            int pl = p0 + w * 8 + j;
            bool ok = pl < myLen;
            pids[j] = ok ? pidxL[pl] : -1;
            pinv[j] = ok ? invL[pl] : 0.f;
        }
        // ---- stage x transposed: lane = column c within group, 8 points packed per b128
        #pragma unroll
        for (int cg = 0; cg < 4; ++cg) {
            int c = cg * 64 + lane;
            float vals[8];
            #pragma unroll
            for (int j = 0; j < 8; ++j) {
                float v = 0.f;
                if (pids[j] >= 0) v = feat[(size_t)pids[j] * 256 + c] * pinv[j];
                vals[j] = v;
            }
            bf16x8 vh, vl;
            #pragma unroll
            for (int j = 0; j < 8; ++j) {
                unsigned u = __float_as_uint(vals[j]);
                float r = vals[j] - __uint_as_float(u & 0xffff0000u);
                vh[j] = (short)(u >> 16);
                vl[j] = (short)(__float_as_uint(r) >> 16);
            }
            *(bf16x8*)&xsT_hi[c * 32 + w * 8] = vh;
            *(bf16x8*)&xsT_lo[c * 32 + w * 8] = vl;
        }
        // ---- stage soft transposed: lane = cluster k
        {
            float svals[8];
            #pragma unroll
            for (int j = 0; j < 8; ++j) {
                float v = 0.f;
                if (pids[j] >= 0) v = soft[(size_t)pids[j] * 64 + lane];
                svals[j] = v;
                sacc += v;
            }
            bf16x8 vh, vl;
            #pragma unroll
            for (int j = 0; j < 8; ++j) {
                unsigned u = __float_as_uint(svals[j]);
                float r = svals[j] - __uint_as_float(u & 0xffff0000u);
                vh[j] = (short)(u >> 16);
                vl[j] = (short)(__float_as_uint(r) >> 16);
            }
            *(bf16x8*)&sT_hi[lane * 32 + w * 8] = vh;
            *(bf16x8*)&sT_lo[lane * 32 + w * 8] = vl;
        }
        __syncthreads();
        // ---- compute: A = soft^T (clusters x points), B = x (points x cols)
        bf16x8 ah = *(const bf16x8*)&sT_hi[(w * 16 + m) * 32 + quad * 8];
        bf16x8 al = *(const bf16x8*)&sT_lo[(w * 16 + m) * 32 + quad * 8];
        #pragma unroll
        for (int ct = 0; ct < 16; ++ct) {
            bf16x8 bh = *(const bf16x8*)&xsT_hi[(ct * 16 + m) * 32 + quad * 8];
            bf16x8 bl = *(const bf16x8*)&xsT_lo[(ct * 16 + m) * 32 + quad * 8];
            acc[ct] = __builtin_amdgcn_mfma_f32_16x16x32_bf16(ah, bh, acc[ct], 0, 0, 0);
            acc[ct] = __builtin_amdgcn_mfma_f32_16x16x32_bf16(ah, bl, acc[ct], 0, 0, 0);
            acc[ct] = __builtin_amdgcn_mfma_f32_16x16x32_bf16(al, bh, acc[ct], 0, 0, 0);
        }
        __syncthreads();
    }

    // ---- write this block's partial 64x256 tile (no atomics)
    float* dst = partial + (size_t)(b * split + sp) * 64 * 256;
    #pragma unroll
    for (int ct = 0; ct < 16; ++ct) {
        #pragma unroll
        for (int r = 0; r < 4; ++r) {
            int k = w * 16 + quad * 4 + r;
            dst[k * 256 + ct * 16 + m] = acc[ct][r];
        }
    }
    atomicAdd(S + b * 64 + lane, sacc);
}

// ---------------- Phase 4a: reduce partials, subtract S*centroid, intra-normalize ----------------
__global__ __launch_bounds__(256) void p4a_vlad(
    const float* __restrict__ partial, const float* __restrict__ S,
    const float* __restrict__ cents, float* __restrict__ v, int split)
{
    const int b = blockIdx.x >> 6, k = blockIdx.x & 63;
    const int t = threadIdx.x;
    float sum = 0.f;
    const float* base = partial + ((size_t)(b * split) * 64 + k) * 256 + t;
    for (int sp = 0; sp < split; ++sp)
        sum += base[(size_t)sp * 64 * 256];
    float val = sum - S[b * 64 + k] * cents[k * 256 + t];
    float sq = val * val;
    #pragma unroll
    for (int off = 32; off >= 1; off >>= 1) sq += __shfl_xor(sq, off);
    __shared__ float wsum[4];
    if ((t & 63) == 0) wsum[t >> 6] = sq;
    __syncthreads();
    float tot = wsum[0] + wsum[1] + wsum[2] + wsum[3];
    float r = 1.0f / fmaxf(sqrtf(tot), 1e-12f);
    v[b * 16384 + k * 256 + t] = val * r;
}

// ---------------- Phase 4b: FC out = v @ fc_w.T + fc_b ----------------
__global__ __launch_bounds__(256) void p4b_fc(
    const float* __restrict__ v, const float* __restrict__ fcw,
    const float* __restrict__ fcb, float* __restrict__ pre)
{
    const int t = threadIdx.x;
    const int o0 = blockIdx.x * 4;
    float acc[4][8] = {};
    for (int it = 0; it < 64; ++it) {
        int i = it * 256 + t;
        float wv[4];
        #pragma unroll
        for (int oo = 0; oo < 4; ++oo) wv[oo] = fcw[(size_t)(o0 + oo) * 16384 + i];
        #pragma unroll
        for (int b = 0; b < 8; ++b) {
            float vv = v[b * 16384 + i];
            #pragma unroll
            for (int oo = 0; oo < 4; ++oo) acc[oo][b] += wv[oo] * vv;
        }
    }
    __shared__ float red[32][4];
    #pragma unroll
    for (int oo = 0; oo < 4; ++oo)
        #pragma unroll
        for (int b = 0; b < 8; ++b) {
            float sv = acc[oo][b];
            #pragma unroll
            for (int off = 32; off >= 1; off >>= 1) sv += __shfl_xor(sv, off);
            if ((t & 63) == 0) red[oo * 8 + b][t >> 6] = sv;
        }
    __syncthreads();
    if (t < 32) {
        int oo = t >> 3, b = t & 7;
        float sv = red[t][0] + red[t][1] + red[t][2] + red[t][3];
        pre[b * 1024 + o0 + oo] = sv + fcb[o0 + oo];
    }
}

// ---------------- Phase 5: final l2norm over 1024 ----------------
__global__ __launch_bounds__(256) void p5_norm(const float* __restrict__ pre, float* __restrict__ out)
{
    const int b = blockIdx.x, t = threadIdx.x;
    float vals[4];
    float sq = 0.f;
    #pragma unroll
    for (int i = 0; i < 4; ++i) {
        vals[i] = pre[b * 1024 + t + 256 * i];
        sq += vals[i] * vals[i];
    }
    #pragma unroll
    for (int off = 32; off >= 1; off >>= 1) sq += __shfl_xor(sq, off);
    __shared__ float wsum[4];
    if ((t & 63) == 0) wsum[t >> 6] = sq;
    __syncthreads();
    float tot = wsum[0] + wsum[1] + wsum[2] + wsum[3];
    float r = 1.0f / fmaxf(sqrtf(tot), 1e-12f);
    #pragma unroll
    for (int i = 0; i < 4; ++i) out[b * 1024 + t + 256 * i] = vals[i] * r;
}

extern "C" void kernel_launch(void* const* d_in, const int* in_sizes, int n_in,
                              void* d_out, int out_size, void* d_ws, size_t ws_size,
                              hipStream_t stream)
{
    const float* feat  = (const float*)d_in[0];
    const int*   bids  = (const int*)d_in[1];
    const float* cents = (const float*)d_in[2];
    const float* convw = (const float*)d_in[3];
    const float* convb = (const float*)d_in[4];
    const float* fcw   = (const float*)d_in[5];
    const float* fcb   = (const float*)d_in[6];
    float* out = (float*)d_out;

    const int N = in_sizes[0] / 256;  // 200000

    // ---- adaptive SPLIT: pick largest partial buffer that fits the workspace
    const size_t base_floats = 16384 /*whi/wlo as shorts = 16384 floats*/
                             + (size_t)N * 64 /*soft*/ + N /*invn*/
                             + 512 /*S*/ + 8 * 16384 /*v*/ + 8192 /*pre*/;
    const size_t base_ints = (size_t)N + 8 + 9 + 8;
    int split = 96;
    while (split > 16) {
        size_t tot = (base_floats + (size_t)split * 8 * 16384) * 4 + base_ints * 4;
        if (tot <= ws_size) break;
        split -= 16;
    }

    short* whi = (short*)d_ws;                    // 16384 shorts
    short* wlo = whi + 16384;                     // 16384 shorts
    float* soft = (float*)(wlo + 16384);          // N*64
    float* invn = soft + (size_t)N * 64;          // N
    float* partial = invn + N;                    // split*8*64*256
    float* S    = partial + (size_t)split * 8 * 16384;  // 512
    float* v    = S + 512;                        // 8*16384
    float* pre  = v + 8 * 16384;                  // 8192
    int* perm = (int*)(pre + 8192);               // N
    int* cnts = perm + N;                         // 8
    int* offs = cnts + 8;                         // 9
    int* cur  = offs + 9;                         // 8

    hipMemsetAsync(S, 0, 512 * sizeof(float), stream);
    hipMemsetAsync(cnts, 0, 8 * sizeof(int), stream);

    p0_wsplit<<<8, 256, 0, stream>>>(convw, whi, wlo);
    p1_mfma<<<(N + 63) / 64, 256, 0, stream>>>(feat, bids, whi, wlo, convb, soft, invn, cnts, N);
    p2_offsets<<<1, 64, 0, stream>>>(cnts, offs, cur);
    p2_scatter<<<(N + 255) / 256, 256, 0, stream>>>(bids, cur, perm, N);
    p3_mfma<<<8 * split, 256, 0, stream>>>(feat, soft, invn, perm, offs, partial, S, split);
    p4a_vlad<<<512, 256, 0, stream>>>(partial, S, cents, v, split);
    p4b_fc<<<256, 256, 0, stream>>>(v, fcw, fcb, pre);
    p5_norm<<<8, 256, 0, stream>>>(pre, out);
}